// Round 2
// baseline (1133.927 us; speedup 1.0000x reference)
//
#include <hip/hip_runtime.h>
#include <stdint.h>

// LoRA: y = dropout( (x @ (2 * B@A)^T) ), p=0.1, mask = jax.random.bernoulli(key(42), 0.9)
// x: [4,4096,4096] f32  -> flatten to M=16384 rows, K=4096
// lora_A: [16,4096] f32 ; lora_B: [4096,16] f32 ; out: [16384,4096] f32
//
// Dropout mask (threefry2x32, JAX partitionable layout): counter=(0, i), key=(0,42),
// bits = out0 ^ out1; keep iff u < 0.9f where u = bitcast((bits>>9)|0x3f800000)-1.
// Integer-exact equivalent: keep iff bits < 0xE6666600u
//   (0.9f*2^23 == 7549747 == 0x733333 exactly; f-1.0 is Sterbenz-exact,
//    so u < 0.9f  <=>  (bits>>9) < 0x733333  <=>  bits < 0x733333<<9).
// The 1/0.9 inverted-dropout scale is folded into pass-1's output scale
// (2.0 * (1/0.9)); dropped elements are written as exact 0.0f.

#define M_TOTAL 16384
#define IN_F 4096
#define OUT_F 4096

__device__ __forceinline__ uint32_t tf_bits(uint32_t idx) {
  const uint32_t ks0 = 0u;
  const uint32_t ks1 = 42u;
  const uint32_t ks2 = 0u ^ 42u ^ 0x1BD11BDAu;
  uint32_t x0 = 0u + ks0;      // counts_hi = 0 (N < 2^32)
  uint32_t x1 = idx + ks1;     // counts_lo = flat index
#define TFR(r) { x0 += x1; x1 = (x1 << (r)) | (x1 >> (32 - (r))); x1 ^= x0; }
  TFR(13) TFR(15) TFR(26) TFR(6)   x0 += ks1; x1 += ks2 + 1u;
  TFR(17) TFR(29) TFR(16) TFR(24)  x0 += ks2; x1 += ks0 + 2u;
  TFR(13) TFR(15) TFR(26) TFR(6)   x0 += ks0; x1 += ks1 + 3u;
  TFR(17) TFR(29) TFR(16) TFR(24)  x0 += ks1; x1 += ks2 + 4u;
  TFR(13) TFR(15) TFR(26) TFR(6)   x0 += ks2; x1 += ks0 + 5u;
#undef TFR
  return x0 ^ x1;   // partitionable 32-bit draw: out0 ^ out1
}

// ---------------- Pass 1: t[m, r] = (2/0.9) * sum_i x[m,i] * A[r,i] ----------
// Round-1 post-mortem: 224 us was per-j-step VMEM serialization (16 A-loads
// round-tripping to cache at ~840 cyc each; no VGPRs to batch them).
// Fix: A staged in LDS in 64 KB k-chunks; inner loop has only 4 independent
// prefetched x-loads + 16 conflict-free ds_read_b128 + 256 FMAs.
// 32-lane groups, each group owns 4 rows; butterfly reduce in-wave at the end.
__global__ __launch_bounds__(256, 2) void lora_xa_kernel(
    const float* __restrict__ x, const float* __restrict__ A,
    float* __restrict__ t) {
  __shared__ float4 As[16 * 256];    // one k-chunk of A: [16 rows][1024 floats] = 64 KB
  const int tid = threadIdx.x;
  const int g = tid >> 5;            // group 0..7 (32 lanes each)
  const int c = tid & 31;            // k-chunk lane within group
  const int m0 = blockIdx.x * 32 + g * 4;

  const float4* A4 = (const float4*)A;                       // [16][1024]
  const float4* xr0 = (const float4*)x + (size_t)m0 * 1024;  // 4 rows

  float acc[4][16];
#pragma unroll
  for (int tt = 0; tt < 4; ++tt)
#pragma unroll
    for (int r = 0; r < 16; ++r) acc[tt][r] = 0.0f;

  // Prefetch x for global step jj=0.
  float4 xv[4];
#pragma unroll
  for (int tt = 0; tt < 4; ++tt) xv[tt] = xr0[tt * 1024 + c];

  for (int chunk = 0; chunk < 4; ++chunk) {
    if (chunk) __syncthreads();      // previous chunk's LDS reads complete
    // Stage A[0:16][chunk*1024 : +1024] -> LDS. 16 coalesced float4 per thread.
#pragma unroll
    for (int i = 0; i < 16; ++i)
      As[i * 256 + tid] = A4[i * 1024 + chunk * 256 + tid];
    __syncthreads();

#pragma unroll
    for (int j = 0; j < 8; ++j) {
      const int jj = chunk * 8 + j;
      // Prefetch next step's x (wraps harmlessly to 0 on the last step).
      const int jn = (jj + 1) & 31;
      float4 xn[4];
#pragma unroll
      for (int tt = 0; tt < 4; ++tt) xn[tt] = xr0[tt * 1024 + jn * 32 + c];

#pragma unroll
      for (int r = 0; r < 16; ++r) {
        const float4 av = As[r * 256 + j * 32 + c];   // LDS, conflict-free b128
#pragma unroll
        for (int tt = 0; tt < 4; ++tt)
          acc[tt][r] += xv[tt].x * av.x + xv[tt].y * av.y +
                        xv[tt].z * av.z + xv[tt].w * av.w;
      }
#pragma unroll
      for (int tt = 0; tt < 4; ++tt) xv[tt] = xn[tt];
    }
  }

  // Butterfly reduce across the 32 lanes of the group (xor offs stay in-group).
#pragma unroll
  for (int off = 1; off <= 16; off <<= 1)
#pragma unroll
    for (int tt = 0; tt < 4; ++tt)
#pragma unroll
      for (int r = 0; r < 16; ++r)
        acc[tt][r] += __shfl_xor(acc[tt][r], off, 64);

  // All 32 lanes hold full sums. Lanes 0-15 write rows m0,m0+1 (col rr);
  // lanes 16-31 write rows m0+2,m0+3. Static-index select via cndmask chain.
  const int rr = c & 15;
  float s[4];
#pragma unroll
  for (int tt = 0; tt < 4; ++tt) {
    float v = acc[tt][0];
#pragma unroll
    for (int r = 1; r < 16; ++r) v = (rr == r) ? acc[tt][r] : v;
    s[tt] = v;
  }
  const bool hi = (c >= 16);
  const float scale = 2.0f / 0.9f;   // SCALING * inverted-dropout 1/keep
  const int mrow = m0 + (hi ? 2 : 0);
  t[(size_t)mrow * 16 + rr]       = (hi ? s[2] : s[0]) * scale;
  t[(size_t)(mrow + 1) * 16 + rr] = (hi ? s[3] : s[1]) * scale;
}

// ---------------- Pass 2: y[m,o] = mask ? sum_r t[m,r] * B[o,r] : 0 ----------
// Block: 64 rows x 1024 cols. Thread owns 4 consecutive cols (B frag in regs),
// loops 64 rows with t staged in LDS (broadcast reads). Dropout is a single
// integer compare per element; scale already folded into t.
__global__ __launch_bounds__(256) void lora_tb_kernel(
    const float* __restrict__ t, const float* __restrict__ B,
    float* __restrict__ y) {
  __shared__ float ts[64 * 16];   // 4 KB
  const int tid = threadIdx.x;
  const int colblk = blockIdx.x & 3;        // 4 col-blocks of 1024
  const int rowblk = blockIdx.x >> 2;       // 256 row-blocks of 64
  const int m0 = rowblk * 64;
  const int o = colblk * 1024 + tid * 4;    // this thread's first column

  // Stage t rows for this block: 1024 floats = 256 float4.
  ((float4*)ts)[tid] = ((const float4*)(t + (size_t)m0 * 16))[tid];

  // Load B[o..o+3][0..15] into registers: 16 float4 (64 VGPRs).
  float4 b[4][4];
#pragma unroll
  for (int c = 0; c < 4; ++c) {
#pragma unroll
    for (int q = 0; q < 4; ++q)
      b[c][q] = ((const float4*)(B + (size_t)(o + c) * 16))[q];
  }
  __syncthreads();

#pragma unroll 2
  for (int mi = 0; mi < 64; ++mi) {
    const int m = m0 + mi;
    float tr[16];
#pragma unroll
    for (int r = 0; r < 16; ++r) tr[r] = ts[mi * 16 + r];  // LDS broadcast

    float accv[4];
#pragma unroll
    for (int c = 0; c < 4; ++c) {
      float s = 0.0f;
#pragma unroll
      for (int q = 0; q < 4; ++q) {
        const float4 bb = b[c][q];
        s += tr[4 * q + 0] * bb.x + tr[4 * q + 1] * bb.y +
             tr[4 * q + 2] * bb.z + tr[4 * q + 3] * bb.w;
      }
      accv[c] = s;
    }

    const uint32_t base = (uint32_t)m * (uint32_t)OUT_F + (uint32_t)o;
    float4 res;
    res.x = (tf_bits(base + 0u) < 0xE6666600u) ? accv[0] : 0.0f;
    res.y = (tf_bits(base + 1u) < 0xE6666600u) ? accv[1] : 0.0f;
    res.z = (tf_bits(base + 2u) < 0xE6666600u) ? accv[2] : 0.0f;
    res.w = (tf_bits(base + 3u) < 0xE6666600u) ? accv[3] : 0.0f;
    ((float4*)y)[((size_t)m * OUT_F + o) >> 2] = res;
  }
}

extern "C" void kernel_launch(void* const* d_in, const int* in_sizes, int n_in,
                              void* d_out, int out_size, void* d_ws, size_t ws_size,
                              hipStream_t stream) {
  const float* x = (const float*)d_in[0];   // [16384, 4096]
  const float* A = (const float*)d_in[1];   // [16, 4096]
  const float* B = (const float*)d_in[2];   // [4096, 16]
  float* y = (float*)d_out;                 // [16384, 4096]
  float* t = (float*)d_ws;                  // [16384, 16] scratch (1 MB)

  lora_xa_kernel<<<M_TOTAL / 32, 256, 0, stream>>>(x, A, t);
  lora_tb_kernel<<<(M_TOTAL / 64) * (OUT_F / 1024), 256, 0, stream>>>(t, B, y);
}

// Round 4
// 574.432 us; speedup vs baseline: 1.9740x; 1.9740x over previous
//
#include <hip/hip_runtime.h>
#include <stdint.h>

// LoRA fused: y = dropout( (x @ (2 * B@A)^T) ), p=0.1, mask = bernoulli(key(42), 0.9)
// x: [4,4096,4096] f32 -> M=16384 rows, K=4096
// lora_A: [16,4096] ; lora_B: [4096,16] ; y: [16384,4096]
//
// Dropout (threefry2x32, JAX partitionable layout): counter=(0,i), key=(0,42),
// bits = out0 ^ out1; keep iff bits < 0xE6666600u  (integer-exact equivalent of
// u < 0.9f: 0.9f*2^23 == 0x733333 exactly; (bits>>9)|1.0f - 1.0 is Sterbenz-exact).
// Inverted-dropout 1/0.9 and SCALING=2 folded into the t scale; drops are exact 0.
//
// Round-2 post-mortem: T=4 + LDS + prefetch arrays -> 128 VGPR cap hit, 1.2 GB
// of scratch spills. Round 0/1 were latency-bound: per-wave serial VMEM chains
// (~500-840 cy per load, zero MLP). This version fuses both passes in one
// kernel with tiny per-thread state:
//   Phase A: A in LDS (8 x 32KB chunks), acc[16] only, prefetched x stream.
//   Phase B: t stays in LDS; B-frag in regs; threefry dropout; y streamed out.
// Grid = 1024 blocks = exactly 4 blocks/CU co-resident (LDS 33KB, VGPR<=128).
// Round 3: container-level infra failure (no verifier result) -> resubmitted
// unchanged to measure the fusion theory cleanly.

#define M_TOTAL 16384
#define IN_F 4096
#define OUT_F 4096

__device__ __forceinline__ uint32_t tf_bits(uint32_t idx) {
  const uint32_t ks0 = 0u;
  const uint32_t ks1 = 42u;
  const uint32_t ks2 = 0u ^ 42u ^ 0x1BD11BDAu;
  uint32_t x0 = 0u + ks0;      // counts_hi = 0 (N < 2^32)
  uint32_t x1 = idx + ks1;     // counts_lo = flat index
#define TFR(r) { x0 += x1; x1 = (x1 << (r)) | (x1 >> (32 - (r))); x1 ^= x0; }
  TFR(13) TFR(15) TFR(26) TFR(6)   x0 += ks1; x1 += ks2 + 1u;
  TFR(17) TFR(29) TFR(16) TFR(24)  x0 += ks2; x1 += ks0 + 2u;
  TFR(13) TFR(15) TFR(26) TFR(6)   x0 += ks0; x1 += ks1 + 3u;
  TFR(17) TFR(29) TFR(16) TFR(24)  x0 += ks1; x1 += ks2 + 4u;
  TFR(13) TFR(15) TFR(26) TFR(6)   x0 += ks2; x1 += ks0 + 5u;
#undef TFR
  return x0 ^ x1;   // partitionable 32-bit draw: out0 ^ out1
}

__global__ __launch_bounds__(256, 4) void lora_fused_kernel(
    const float* __restrict__ x, const float* __restrict__ A,
    const float* __restrict__ B, float* __restrict__ y) {
  __shared__ float4 As[16 * 128];   // 32 KB: A[0:16][ck*512 .. +512) as float4
  __shared__ float ts[16 * 16];     // 1 KB: t rows for this block

  const int tid = threadIdx.x;
  const int row = tid >> 4;          // 0..15  (x-row within block)
  const int c = tid & 15;            // 0..15  (k-chunk lane)
  const int m0 = blockIdx.x * 16;

  const float4* x4 = (const float4*)x + (size_t)(m0 + row) * 1024;
  const float4* A4 = (const float4*)A;   // [16][1024]

  // ---------------- Phase A: t[row, r] = (2/0.9) * sum_k x[row,k]*A[r,k] ----
  float acc[16];
#pragma unroll
  for (int r = 0; r < 16; ++r) acc[r] = 0.0f;

  float4 xv = x4[c];                 // prefetch for jj=0

  for (int ck = 0; ck < 8; ++ck) {
    if (ck) __syncthreads();         // prior chunk's LDS reads done
    // Stage A[0:16][ck*512 .. +512) -> LDS: 2048 float4, 8 per thread, coalesced.
#pragma unroll
    for (int i = 0; i < 8; ++i) {
      const int idx = tid + i * 256;          // 0..2047
      const int r = idx >> 7, col = idx & 127;
      As[r * 128 + col] = A4[r * 1024 + ck * 128 + col];
    }
    __syncthreads();

#pragma unroll
    for (int j = 0; j < 8; ++j) {
      const int jj = ck * 8 + j;
      const int jn = (jj + 1) & 63;           // wraps harmlessly at the end
      const float4 xn = x4[jn * 16 + c];      // prefetch next step's x

#pragma unroll
      for (int r = 0; r < 16; ++r) {
        const float4 av = As[r * 128 + j * 16 + c];  // broadcast, 2-way max
        acc[r] += xv.x * av.x + xv.y * av.y + xv.z * av.z + xv.w * av.w;
      }
      xv = xn;
    }
  }

  // Reduce across the 16 lanes of each row-group (xor offs stay in-group).
#pragma unroll
  for (int off = 1; off < 16; off <<= 1)
#pragma unroll
    for (int r = 0; r < 16; ++r) acc[r] += __shfl_xor(acc[r], off, 64);

  // All 16 lanes hold all sums; lane c keeps element c (static cndmask chain).
  float out = acc[0];
#pragma unroll
  for (int r = 1; r < 16; ++r) out = (c == r) ? acc[r] : out;
  ts[row * 16 + c] = out * (2.0f / 0.9f);   // SCALING * 1/keep
  __syncthreads();

  // ---------------- Phase B: y[m, o] = mask ? sum_r t[m,r]*B[o,r] : 0 -------
  const float4* B4 = (const float4*)B;      // [4096][4] float4 rows
  float4* y4 = (float4*)y;

  for (int cs = 0; cs < 4; ++cs) {
    const int o = cs * 1024 + tid * 4;      // this thread's first column
    float4 b[4][4];                         // B[o..o+3][0..15]: 16 float4
#pragma unroll
    for (int cc = 0; cc < 4; ++cc)
#pragma unroll
      for (int q = 0; q < 4; ++q)
        b[cc][q] = B4[(o + cc) * 4 + q];

    for (int mi = 0; mi < 16; ++mi) {
      const float4* trow = (const float4*)&ts[mi * 16];  // broadcast b128 reads
      const float4 t0 = trow[0], t1 = trow[1], t2 = trow[2], t3 = trow[3];

      float accv[4];
#pragma unroll
      for (int cc = 0; cc < 4; ++cc) {
        accv[cc] = t0.x * b[cc][0].x + t0.y * b[cc][0].y +
                   t0.z * b[cc][0].z + t0.w * b[cc][0].w +
                   t1.x * b[cc][1].x + t1.y * b[cc][1].y +
                   t1.z * b[cc][1].z + t1.w * b[cc][1].w +
                   t2.x * b[cc][2].x + t2.y * b[cc][2].y +
                   t2.z * b[cc][2].z + t2.w * b[cc][2].w +
                   t3.x * b[cc][3].x + t3.y * b[cc][3].y +
                   t3.z * b[cc][3].z + t3.w * b[cc][3].w;
      }

      const uint32_t base = (uint32_t)(m0 + mi) * (uint32_t)OUT_F + (uint32_t)o;
      float4 res;
      res.x = (tf_bits(base + 0u) < 0xE6666600u) ? accv[0] : 0.0f;
      res.y = (tf_bits(base + 1u) < 0xE6666600u) ? accv[1] : 0.0f;
      res.z = (tf_bits(base + 2u) < 0xE6666600u) ? accv[2] : 0.0f;
      res.w = (tf_bits(base + 3u) < 0xE6666600u) ? accv[3] : 0.0f;
      y4[((size_t)(m0 + mi) * OUT_F + o) >> 2] = res;
    }
  }
}

extern "C" void kernel_launch(void* const* d_in, const int* in_sizes, int n_in,
                              void* d_out, int out_size, void* d_ws, size_t ws_size,
                              hipStream_t stream) {
  const float* x = (const float*)d_in[0];   // [16384, 4096]
  const float* A = (const float*)d_in[1];   // [16, 4096]
  const float* B = (const float*)d_in[2];   // [4096, 16]
  float* y = (float*)d_out;                 // [16384, 4096]

  lora_fused_kernel<<<M_TOTAL / 16, 256, 0, stream>>>(x, A, B, y);
}